// Round 1
// 979.154 us; speedup vs baseline: 1.7553x; 1.7553x over previous
//
#include <hip/hip_runtime.h>
#include <stdint.h>

// Fused attention: out = dropout(softmax(Q K^T * scale + mask)) @ V
// B=1, H=128, S=256, D=2048, fp32 in/out.
// Round 2: f16 MFMA (32x32x16) for both matmuls, fp32 accumulate.
//   - Phase 1 (QK^T): fragments loaded straight from global (no LDS/barriers),
//     4 waves split the 256 keys, acc = 64q x 64k per wave.
//   - Phase 2: register softmax + shuffle/LDS row reduce; threefry dropout
//     precomputed into a 2KB LDS bitmask (bit-exact vs previous kernel).
//   - Phase 3 (PV): P staged in LDS as f16, V streamed global->frag.
// Error budget: f16 rounding adds <~3e-3 abs vs the fp32 kernel's 0.03125.

#define NH   128
#define SEQ  256
#define DIM  2048
#define TQ   64
#define NTHR 256
#define PLDP 264   // P_lds row stride in halves (528 B: 16B-aligned, 4-way ok)

using f16x8  = __attribute__((ext_vector_type(8)))  _Float16;
using f32x16 = __attribute__((ext_vector_type(16))) float;

// ---------- threefry2x32, JAX key = random.key(42) -> (k0,k1)=(0,42) --------
// bits[i] = x0 ^ x1 of threefry2x32(key, (0, i))   (partitionable mode)
#define THREEFRY_PARTITIONABLE 1

__device__ __forceinline__ uint32_t rotl32(uint32_t v, uint32_t d) {
  return (v << d) | (v >> (32u - d));
}
__device__ __forceinline__ void tf4(uint32_t& x0, uint32_t& x1,
                                    int r0, int r1, int r2, int r3) {
  x0 += x1; x1 = rotl32(x1, r0); x1 ^= x0;
  x0 += x1; x1 = rotl32(x1, r1); x1 ^= x0;
  x0 += x1; x1 = rotl32(x1, r2); x1 ^= x0;
  x0 += x1; x1 = rotl32(x1, r3); x1 ^= x0;
}
__device__ __forceinline__ uint2 tf2x32(uint32_t x0, uint32_t x1) {
  const uint32_t K0 = 0u, K1 = 42u, K2 = (0u ^ 42u ^ 0x1BD11BDAu);
  x0 += K0; x1 += K1;
  tf4(x0, x1, 13, 15, 26, 6);   x0 += K1; x1 += K2 + 1u;
  tf4(x0, x1, 17, 29, 16, 24);  x0 += K2; x1 += K0 + 2u;
  tf4(x0, x1, 13, 15, 26, 6);   x0 += K0; x1 += K1 + 3u;
  tf4(x0, x1, 17, 29, 16, 24);  x0 += K1; x1 += K2 + 4u;
  tf4(x0, x1, 13, 15, 26, 6);   x0 += K2; x1 += K0 + 5u;
  return make_uint2(x0, x1);
}
__device__ __forceinline__ bool keep_mask(uint32_t i) {
  uint32_t b;
#if THREEFRY_PARTITIONABLE
  { uint2 r = tf2x32(0u, i); b = r.x ^ r.y; }
#else
  const uint32_t HALF = 4194304u;  // 8388608/2
  if (i < HALF) { uint2 r = tf2x32(i, i + HALF); b = r.x; }
  else          { uint2 r = tf2x32(i - HALF, i); b = r.y; }
#endif
  float u = __uint_as_float((b >> 9) | 0x3f800000u) - 1.0f;
  return u < 0.1f;
}

__device__ __forceinline__ f16x8 cvt8(float4 a, float4 b) {
  f16x8 r;
  r[0] = (_Float16)a.x; r[1] = (_Float16)a.y;
  r[2] = (_Float16)a.z; r[3] = (_Float16)a.w;
  r[4] = (_Float16)b.x; r[5] = (_Float16)b.y;
  r[6] = (_Float16)b.z; r[7] = (_Float16)b.w;
  return r;
}

__device__ __forceinline__ f32x16 zero16() {
  f32x16 z;
#pragma unroll
  for (int i = 0; i < 16; ++i) z[i] = 0.0f;
  return z;
}

__global__ __launch_bounds__(NTHR, 2)
void attn_fused(const float* __restrict__ Q, const float* __restrict__ K,
                const float* __restrict__ V, const float* __restrict__ M,
                float* __restrict__ O)
{
  __shared__ __align__(16) _Float16 Pl[TQ][PLDP];       // 33 KB  P as f16
  __shared__ __align__(16) float    redm[TQ][4];        // 1 KB   rowmax partials
  __shared__ __align__(16) float    reds[TQ][4];        // 1 KB   rowsum partials
  __shared__ uint32_t               keepb[TQ][SEQ/32];  // 2 KB   dropout bits

  const int t  = threadIdx.x;
  const int w  = t >> 6;          // wave 0..3
  const int ln = t & 31;          // lane & 31  (MFMA row/col index)
  const int hi = (t >> 5) & 1;    // lane >> 5  (MFMA k-half / row+4 select)
  const int h8 = hi * 8;

  const int blk = blockIdx.x;
  // XCD swizzle: the 4 q-blocks of one head share an XCD so K_h+V_h (4 MB)
  // stays L2-resident. xcd = blk % 8 heuristic; bijective over 512 blocks.
  const int a  = blk & 7;
  const int s_ = blk >> 3;
  const int h  = (a << 4) | (s_ >> 2);   // 0..127
  const int q0 = (s_ & 3) * TQ;

  const float* __restrict__ Qh = Q + (size_t)h * SEQ * DIM;
  const float* __restrict__ Kh = K + (size_t)h * SEQ * DIM;
  const float* __restrict__ Vh = V + (size_t)h * SEQ * DIM;
  float* __restrict__       Oh = O + (size_t)h * SEQ * DIM;

  const int kb = w * 64;          // this wave's key slice [kb, kb+64)

  // ============ phase 1: S = Q K^T via f16 MFMA, frags from global =========
  // A-frag (Q): lane holds Q[q0 + ln][d0 + h8 + j], j=0..7  (rows ln, ln+32)
  // B-frag (K^T): lane holds K[kb + ln][d0 + h8 + j]        (keys ln, ln+32)
  f32x16 a00 = zero16(), a01 = zero16(), a10 = zero16(), a11 = zero16();
  {
    const float* qp0 = Qh + (size_t)(q0 + ln) * DIM + h8;
    const float* qp1 = qp0 + 32 * DIM;
    const float* kp0 = Kh + (size_t)(kb + ln) * DIM + h8;
    const float* kp1 = kp0 + 32 * DIM;
#pragma unroll 2
    for (int d0 = 0; d0 < DIM; d0 += 16) {
      float4 qa = *(const float4*)(qp0 + d0);
      float4 qb = *(const float4*)(qp0 + d0 + 4);
      float4 qc = *(const float4*)(qp1 + d0);
      float4 qd = *(const float4*)(qp1 + d0 + 4);
      float4 ka = *(const float4*)(kp0 + d0);
      float4 kb4 = *(const float4*)(kp0 + d0 + 4);
      float4 kc = *(const float4*)(kp1 + d0);
      float4 kd = *(const float4*)(kp1 + d0 + 4);
      f16x8 A0 = cvt8(qa, qb), A1 = cvt8(qc, qd);
      f16x8 B0 = cvt8(ka, kb4), B1 = cvt8(kc, kd);
      a00 = __builtin_amdgcn_mfma_f32_32x32x16_f16(A0, B0, a00, 0, 0, 0);
      a01 = __builtin_amdgcn_mfma_f32_32x32x16_f16(A0, B1, a01, 0, 0, 0);
      a10 = __builtin_amdgcn_mfma_f32_32x32x16_f16(A1, B0, a10, 0, 0, 0);
      a11 = __builtin_amdgcn_mfma_f32_32x32x16_f16(A1, B1, a11, 0, 0, 0);
    }
  }

  // ============ dropout keep-bits -> LDS bitmask (compact runtime loop) ====
  // thread t covers row = t>>2, keys [(t&3)*64, +64): 2 uint32 words.
  {
    uint32_t w0 = 0, w1 = 0;
    const uint32_t ib = ((uint32_t)h << 16) | ((uint32_t)(q0 + (t >> 2)) << 8)
                      | (uint32_t)((t & 3) * 64);
    for (int j = 0; j < 32; ++j) {
      w0 |= (keep_mask(ib + (uint32_t)j)       ? 1u : 0u) << j;
      w1 |= (keep_mask(ib + 32u + (uint32_t)j) ? 1u : 0u) << j;
    }
    keepb[t >> 2][(t & 3) * 2 + 0] = w0;
    keepb[t >> 2][(t & 3) * 2 + 1] = w1;
  }

  // ============ phase 2: softmax + dropout, register resident ==============
  // C/D layout (32x32): col = ln, row = (r&3) + 8*(r>>2) + 4*hi  (+32 for qi=1)
  const float scale = 0.022097086912079608f;  // 1/sqrt(2048)
  float p[2][2][16];
  float mx[2][16];
  {
    const float* Mb = M + (size_t)q0 * SEQ + kb + ln;
#pragma unroll
    for (int qi = 0; qi < 2; ++qi)
#pragma unroll
      for (int r = 0; r < 16; ++r) {
        const int row = qi * 32 + (r & 3) + 8 * (r >> 2) + 4 * hi;
        const float m0 = Mb[(size_t)row * SEQ];
        const float m1 = Mb[(size_t)row * SEQ + 32];
        p[qi][0][r] = fmaf(qi ? a10[r] : a00[r], scale, m0);
        p[qi][1][r] = fmaf(qi ? a11[r] : a01[r], scale, m1);
        mx[qi][r] = fmaxf(p[qi][0][r], p[qi][1][r]);
      }
  }
  // row max: shuffle across the 32 cols, then cross-wave via LDS
#pragma unroll
  for (int st = 1; st <= 16; st <<= 1)
#pragma unroll
    for (int qi = 0; qi < 2; ++qi)
#pragma unroll
      for (int r = 0; r < 16; ++r)
        mx[qi][r] = fmaxf(mx[qi][r], __shfl_xor(mx[qi][r], st));
  if (ln == 0) {
#pragma unroll
    for (int qi = 0; qi < 2; ++qi)
#pragma unroll
      for (int r = 0; r < 16; ++r) {
        const int row = qi * 32 + (r & 3) + 8 * (r >> 2) + 4 * hi;
        redm[row][w] = mx[qi][r];
      }
  }
  __syncthreads();

  float sm[2][16];
#pragma unroll
  for (int qi = 0; qi < 2; ++qi)
#pragma unroll
    for (int r = 0; r < 16; ++r) {
      const int row = qi * 32 + (r & 3) + 8 * (r >> 2) + 4 * hi;
      const float4 rv = *(const float4*)&redm[row][0];
      const float fm = fmaxf(fmaxf(rv.x, rv.y), fmaxf(rv.z, rv.w));
      p[qi][0][r] = __expf(p[qi][0][r] - fm);
      p[qi][1][r] = __expf(p[qi][1][r] - fm);
      sm[qi][r] = p[qi][0][r] + p[qi][1][r];
    }
#pragma unroll
  for (int st = 1; st <= 16; st <<= 1)
#pragma unroll
    for (int qi = 0; qi < 2; ++qi)
#pragma unroll
      for (int r = 0; r < 16; ++r)
        sm[qi][r] += __shfl_xor(sm[qi][r], st);
  if (ln == 0) {
#pragma unroll
    for (int qi = 0; qi < 2; ++qi)
#pragma unroll
      for (int r = 0; r < 16; ++r) {
        const int row = qi * 32 + (r & 3) + 8 * (r >> 2) + 4 * hi;
        reds[row][w] = sm[qi][r];
      }
  }
  __syncthreads();

  // dropout + P -> LDS as f16
#pragma unroll
  for (int qi = 0; qi < 2; ++qi)
#pragma unroll
    for (int r = 0; r < 16; ++r) {
      const int row = qi * 32 + (r & 3) + 8 * (r >> 2) + 4 * hi;
      const float4 sv = *(const float4*)&reds[row][0];
      const float wsc = 10.0f / (sv.x + sv.y + sv.z + sv.w);  // /l then /0.1
      const uint32_t kw0 = keepb[row][w * 2 + 0];
      const uint32_t kw1 = keepb[row][w * 2 + 1];
      const float v0 = ((kw0 >> ln) & 1u) ? p[qi][0][r] * wsc : 0.0f;
      const float v1 = ((kw1 >> ln) & 1u) ? p[qi][1][r] * wsc : 0.0f;
      Pl[row][kb + ln]      = (_Float16)v0;
      Pl[row][kb + 32 + ln] = (_Float16)v1;
    }
  __syncthreads();

  // ============ phase 3: out = P V via f16 MFMA, V from global =============
  // A-frag (P): lane holds Pl[ln][k0 + h8 + j]   (rows ln, ln+32)
  // B-frag (V): lane holds V[k0 + h8 + j][dbase + ln]  (cols ln, ln+32)
  for (int c = 0; c < 8; ++c) {
    const int dbase = c * 256 + w * 64;   // wave's 64-wide d chunk
    f32x16 o00 = zero16(), o01 = zero16(), o10 = zero16(), o11 = zero16();
    const float* vp = Vh + dbase + ln;
#pragma unroll 2
    for (int k0 = 0; k0 < SEQ; k0 += 16) {
      f16x8 A0 = *(const f16x8*)&Pl[ln][k0 + h8];
      f16x8 A1 = *(const f16x8*)&Pl[32 + ln][k0 + h8];
      f16x8 B0, B1;
      const float* vk = vp + (size_t)(k0 + h8) * DIM;
#pragma unroll
      for (int j = 0; j < 8; ++j) {
        B0[j] = (_Float16)vk[(size_t)j * DIM];
        B1[j] = (_Float16)vk[(size_t)j * DIM + 32];
      }
      o00 = __builtin_amdgcn_mfma_f32_32x32x16_f16(A0, B0, o00, 0, 0, 0);
      o01 = __builtin_amdgcn_mfma_f32_32x32x16_f16(A0, B1, o01, 0, 0, 0);
      o10 = __builtin_amdgcn_mfma_f32_32x32x16_f16(A1, B0, o10, 0, 0, 0);
      o11 = __builtin_amdgcn_mfma_f32_32x32x16_f16(A1, B1, o11, 0, 0, 0);
    }
    float* op = Oh + (size_t)q0 * DIM + dbase + ln;
#pragma unroll
    for (int r = 0; r < 16; ++r) {
      const int row0 = (r & 3) + 8 * (r >> 2) + 4 * hi;
      op[(size_t)row0 * DIM]             = o00[r];
      op[(size_t)row0 * DIM + 32]        = o01[r];
      op[(size_t)(row0 + 32) * DIM]      = o10[r];
      op[(size_t)(row0 + 32) * DIM + 32] = o11[r];
    }
  }
}

extern "C" void kernel_launch(void* const* d_in, const int* in_sizes, int n_in,
                              void* d_out, int out_size, void* d_ws, size_t ws_size,
                              hipStream_t stream) {
  const float* Q = (const float*)d_in[0];
  const float* K = (const float*)d_in[1];
  const float* V = (const float*)d_in[2];
  const float* M = (const float*)d_in[3];
  float* O = (float*)d_out;
  hipLaunchKernelGGL(attn_fused, dim3(NH * (SEQ / TQ)), dim3(NTHR), 0, stream,
                     Q, K, V, M, O);
}